// Round 3
// baseline (376.192 us; speedup 1.0000x reference)
//
#include <hip/hip_runtime.h>
#include <hip/hip_bf16.h>

typedef unsigned short ushort_t;

#define B_ 64
#define S_ 512
#define E_ 256
#define H_ 128
#define M_ (B_ * S_)   // 32768 rows
#define CAP_ 128       // max neighbor slots (nnz ~ Binom(512,0.05): mean 25.6, max ~55)

// ---------------------------------------------------------------------------
// K1: neighbor lists from binary adj (float4 reads; indices unordered within
// row — fp32 summation order tolerance is fine) + invdeg = 1/(nnz+1)
// ---------------------------------------------------------------------------
__global__ void k_adjidx(const float* __restrict__ adj,
                         ushort_t* __restrict__ idxl,
                         int* __restrict__ nnz,
                         float* __restrict__ invdeg) {
    int row  = blockIdx.x * 4 + (threadIdx.x >> 6);
    int lane = threadIdx.x & 63;
    const float4* arow = (const float4*)(adj + (size_t)row * S_);
    ushort_t* dst = idxl + (size_t)row * CAP_;
    int total = 0;
    #pragma unroll
    for (int c = 0; c < 2; ++c) {
        float4 v = arow[c * 64 + lane];
        float f[4] = {v.x, v.y, v.z, v.w};
        #pragma unroll
        for (int j = 0; j < 4; ++j) {
            unsigned long long m = __ballot(f[j] != 0.0f);
            if (f[j] != 0.0f) {
                int pos = total + __popcll(m & ((1ull << lane) - 1ull));
                if (pos < CAP_) dst[pos] = (ushort_t)(c * 256 + lane * 4 + j);
            }
            total += __popcll(m);
        }
    }
    if (lane == 0) {
        nnz[row] = total < CAP_ ? total : CAP_;
        invdeg[row] = 1.0f / (float)(total + 1);
    }
}

// ---------------------------------------------------------------------------
// K2: GEMM  Y[row,:] = X[row,:] @ W^T   (pure matmul; epilogue lives in agg)
// GATHER: X[row,:] = emb[sent[row],:]  (fused embedding, layer 1)
// BM=64 BN=128 BK=16, 256 threads, 8x4 micro-tile.
// Double-buffered LDS + register prefetch, ONE barrier per K-iteration:
//   iter: store regs->LDS[buf]; barrier; prefetch it+1 -> regs; compute buf.
// Safety: store(it+2 -> buf) can't pass barrier(it+1), which waits for all
// waves to finish compute(it) reading buf.
// ---------------------------------------------------------------------------
template <int KDIM, bool GATHER>
__global__ __launch_bounds__(256) void k_gemm(const float* __restrict__ X,
                                              const int* __restrict__ sent,
                                              const float* __restrict__ emb,
                                              const float* __restrict__ W,
                                              float* __restrict__ out) {
    const int BK = 16;
    __shared__ float Xs[2][BK][68];    // [k][m], 2-way-conflict-free stores
    __shared__ float Ws[2][BK][132];   // [k][n]
    int tid = threadIdx.x;
    int rowBlock = blockIdx.x * 64;
    int r0 = (tid >> 5) * 8;        // 0..56
    int c0 = (tid & 31) * 4;        // 0..124
    float acc[8][4] = {};

    int mIdx = tid >> 2;                       // 0..63
    int k4   = (tid & 3) * 4;
    const float* xsrc;
    if (GATHER) xsrc = emb + (size_t)sent[rowBlock + mIdx] * KDIM + k4;
    else        xsrc = X   + (size_t)(rowBlock + mIdx) * KDIM + k4;
    int wj = tid >> 1;                         // 0..127
    int k8 = (tid & 1) * 8;
    const float* wsrc = W + (size_t)wj * KDIM + k8;

    // preload tile 0 into registers
    float4 xf = *(const float4*)(xsrc);
    float4 w0 = *(const float4*)(wsrc);
    float4 w1 = *(const float4*)(wsrc + 4);

    constexpr int NIT = KDIM / BK;
    #pragma unroll
    for (int it = 0; it < NIT; ++it) {
        int buf = it & 1;
        Xs[buf][k4 + 0][mIdx] = xf.x; Xs[buf][k4 + 1][mIdx] = xf.y;
        Xs[buf][k4 + 2][mIdx] = xf.z; Xs[buf][k4 + 3][mIdx] = xf.w;
        Ws[buf][k8 + 0][wj] = w0.x; Ws[buf][k8 + 1][wj] = w0.y;
        Ws[buf][k8 + 2][wj] = w0.z; Ws[buf][k8 + 3][wj] = w0.w;
        Ws[buf][k8 + 4][wj] = w1.x; Ws[buf][k8 + 5][wj] = w1.y;
        Ws[buf][k8 + 6][wj] = w1.z; Ws[buf][k8 + 7][wj] = w1.w;
        __syncthreads();
        if (it + 1 < NIT) {   // prefetch next tile; latency hidden by compute
            xf = *(const float4*)(xsrc + (it + 1) * BK);
            w0 = *(const float4*)(wsrc + (it + 1) * BK);
            w1 = *(const float4*)(wsrc + (it + 1) * BK + 4);
        }
        #pragma unroll
        for (int k = 0; k < BK; ++k) {
            float4 a0 = *(const float4*)&Xs[buf][k][r0];
            float4 a1 = *(const float4*)&Xs[buf][k][r0 + 4];
            float4 wv = *(const float4*)&Ws[buf][k][c0];
            float xv[8] = {a0.x, a0.y, a0.z, a0.w, a1.x, a1.y, a1.z, a1.w};
            #pragma unroll
            for (int i = 0; i < 8; ++i) {
                acc[i][0] += xv[i] * wv.x;
                acc[i][1] += xv[i] * wv.y;
                acc[i][2] += xv[i] * wv.z;
                acc[i][3] += xv[i] * wv.w;
            }
        }
    }

    #pragma unroll
    for (int i = 0; i < 8; ++i) {
        int row = rowBlock + r0 + i;
        float4 o = {acc[i][0], acc[i][1], acc[i][2], acc[i][3]};
        *(float4*)(out + (size_t)row * H_ + c0) = o;
    }
}

// ---------------------------------------------------------------------------
// K3: aggregate + epilogue:
//   h[row] = relu( (Y[row] + sum_{t in nbr(row)} Y[b,t] + 2b) * invdeg[row] )
// 256 threads = 8 rows x 32 float4-lanes; XCD-swizzled so each batch's 256KB
// slab stays in one XCD's L2.
// POOL: instead of writing h, reduce max over the block's 8 rows and write
// partial pp[b*64+g] (fused AdaptiveMaxPool for layer 3).
// ---------------------------------------------------------------------------
template <bool POOL>
__global__ __launch_bounds__(256) void k_aggf(const float* __restrict__ Y,
                                              const ushort_t* __restrict__ idxl,
                                              const int* __restrict__ nnz,
                                              const float* __restrict__ invdeg,
                                              const float* __restrict__ bias,
                                              float* __restrict__ out) {
    int x    = blockIdx.x;            // 0..4095
    int xcd  = x & 7;
    int slot = x >> 3;                // 0..511
    int b    = xcd + 8 * (slot >> 6); // batches 0..63, fixed xcd per batch
    int g    = slot & 63;             // row-group within batch
    int r    = threadIdx.x >> 5;      // 0..7
    int row  = b * S_ + g * 8 + r;
    int c    = threadIdx.x & 31;      // float4 column

    const float4* Y4 = (const float4*)Y;
    int n = nnz[row];
    const ushort_t* il = idxl + (size_t)row * CAP_;
    float4 acc = Y4[(size_t)row * 32 + c];
    float4 acc2 = {0.f, 0.f, 0.f, 0.f};
    size_t base = (size_t)b * S_ * 32;

    int i = 0;
    for (; i + 4 <= n; i += 4) {
        int t0 = il[i], t1 = il[i + 1], t2 = il[i + 2], t3 = il[i + 3];
        float4 v0 = Y4[base + (size_t)t0 * 32 + c];
        float4 v1 = Y4[base + (size_t)t1 * 32 + c];
        float4 v2 = Y4[base + (size_t)t2 * 32 + c];
        float4 v3 = Y4[base + (size_t)t3 * 32 + c];
        acc.x += v0.x + v1.x; acc.y += v0.y + v1.y;
        acc.z += v0.z + v1.z; acc.w += v0.w + v1.w;
        acc2.x += v2.x + v3.x; acc2.y += v2.y + v3.y;
        acc2.z += v2.z + v3.z; acc2.w += v2.w + v3.w;
    }
    for (; i < n; ++i) {
        int t = il[i];
        float4 v = Y4[base + (size_t)t * 32 + c];
        acc.x += v.x; acc.y += v.y; acc.z += v.z; acc.w += v.w;
    }
    acc.x += acc2.x; acc.y += acc2.y; acc.z += acc2.z; acc.w += acc2.w;

    float inv = invdeg[row];
    float4 bv = ((const float4*)bias)[c];
    float4 o;
    o.x = fmaxf((acc.x + 2.0f * bv.x) * inv, 0.0f);
    o.y = fmaxf((acc.y + 2.0f * bv.y) * inv, 0.0f);
    o.z = fmaxf((acc.z + 2.0f * bv.z) * inv, 0.0f);
    o.w = fmaxf((acc.w + 2.0f * bv.w) * inv, 0.0f);

    if (!POOL) {
        ((float4*)out)[(size_t)row * 32 + c] = o;
    } else {
        __shared__ float4 sm[8][33];
        sm[r][c] = o;
        __syncthreads();
        if (r == 0) {
            float4 m = sm[0][c];
            #pragma unroll
            for (int q = 1; q < 8; ++q) {
                float4 v = sm[q][c];
                m.x = fmaxf(m.x, v.x); m.y = fmaxf(m.y, v.y);
                m.z = fmaxf(m.z, v.z); m.w = fmaxf(m.w, v.w);
            }
            ((float4*)out)[((size_t)b * 64 + g) * 32 + c] = m;   // pp partial
        }
    }
}

// ---------------------------------------------------------------------------
// K4: finish pool (64 partials) + logits[b,c] = pooled . Wp[c,:] + bp[c]
// ---------------------------------------------------------------------------
__global__ void k_final(const float* __restrict__ pp,
                        const float* __restrict__ Wp,
                        const float* __restrict__ bp,
                        float* __restrict__ out) {
    int b = blockIdx.x, j = threadIdx.x;  // 128 threads
    const float* p = pp + (size_t)b * 64 * H_ + j;
    float m = -1e30f;
    #pragma unroll 8
    for (int i = 0; i < 64; ++i) m = fmaxf(m, p[(size_t)i * H_]);
    float t0 = m * Wp[j];
    float t1 = m * Wp[H_ + j];
    #pragma unroll
    for (int off = 32; off > 0; off >>= 1) {
        t0 += __shfl_down(t0, off);
        t1 += __shfl_down(t1, off);
    }
    __shared__ float red[2][2];
    int wave = j >> 6, lane = j & 63;
    if (lane == 0) { red[0][wave] = t0; red[1][wave] = t1; }
    __syncthreads();
    if (j == 0) out[b * 2 + 0] = red[0][0] + red[0][1] + bp[0];
    if (j == 1) out[b * 2 + 1] = red[1][0] + red[1][1] + bp[1];
}

// ---------------------------------------------------------------------------
extern "C" void kernel_launch(void* const* d_in, const int* in_sizes, int n_in,
                              void* d_out, int out_size, void* d_ws, size_t ws_size,
                              hipStream_t stream) {
    const int*   sent = (const int*)d_in[0];
    const float* adj  = (const float*)d_in[1];
    const float* emb  = (const float*)d_in[2];
    const float* W1   = (const float*)d_in[3];
    const float* b1   = (const float*)d_in[4];
    const float* W2   = (const float*)d_in[5];
    const float* b2   = (const float*)d_in[6];
    const float* W3   = (const float*)d_in[7];
    const float* b3   = (const float*)d_in[8];
    const float* Wp   = (const float*)d_in[9];
    const float* bp   = (const float*)d_in[10];
    float* out = (float*)d_out;

    char* ws = (char*)d_ws;
    float*    bufA   = (float*)ws;                                  // M*128 f32
    float*    bufB   = (float*)(ws + (size_t)M_ * 256 * 4);         // M*128 f32
    float*    invdeg = (float*)(ws + (size_t)M_ * 512 * 4);         // M f32
    int*      nnz    = (int*)(ws + (size_t)M_ * 512 * 4 + M_ * 4);
    ushort_t* idxl   = (ushort_t*)(ws + (size_t)M_ * 512 * 4 + M_ * 8);          // M*CAP u16
    float*    pp     = (float*)(ws + (size_t)M_ * 512 * 4 + M_ * 8 + (size_t)M_ * CAP_ * 2);  // 64*64*128 f32

    k_adjidx<<<M_ / 4, 256, 0, stream>>>(adj, idxl, nnz, invdeg);

    // layer 1: Y1 = emb[sent] @ W1^T (fused embedding), then agg+epilogue
    k_gemm<E_, true><<<M_ / 64, 256, 0, stream>>>(nullptr, sent, emb, W1, bufA);
    k_aggf<false><<<M_ / 8, 256, 0, stream>>>(bufA, idxl, nnz, invdeg, b1, bufB);

    // layer 2
    k_gemm<H_, false><<<M_ / 64, 256, 0, stream>>>(bufB, nullptr, nullptr, W2, bufA);
    k_aggf<false><<<M_ / 8, 256, 0, stream>>>(bufA, idxl, nnz, invdeg, b2, bufB);

    // layer 3: agg + fused max-pool partials (h3 never materialized)
    k_gemm<H_, false><<<M_ / 64, 256, 0, stream>>>(bufB, nullptr, nullptr, W3, bufA);
    k_aggf<true><<<M_ / 8, 256, 0, stream>>>(bufA, idxl, nnz, invdeg, b3, pp);

    k_final<<<B_, H_, 0, stream>>>(pp, Wp, bp, out);
}

// Round 4
// 303.032 us; speedup vs baseline: 1.2414x; 1.2414x over previous
//
#include <hip/hip_runtime.h>
#include <hip/hip_bf16.h>

typedef unsigned short ushort_t;

#define B_ 64
#define S_ 512
#define E_ 256
#define H_ 128
#define M_ (B_ * S_)   // 32768 rows
#define CAP_ 128       // max neighbor slots (nnz ~ Binom(512,0.05): mean 25.6, max ~55)

// ---------------------------------------------------------------------------
// K1: neighbor lists from binary adj (float4 reads) + invdeg = 1/(nnz+1)
// ---------------------------------------------------------------------------
__global__ void k_adjidx(const float* __restrict__ adj,
                         ushort_t* __restrict__ idxl,
                         int* __restrict__ nnz,
                         float* __restrict__ invdeg) {
    int row  = blockIdx.x * 4 + (threadIdx.x >> 6);
    int lane = threadIdx.x & 63;
    const float4* arow = (const float4*)(adj + (size_t)row * S_);
    ushort_t* dst = idxl + (size_t)row * CAP_;
    int total = 0;
    #pragma unroll
    for (int c = 0; c < 2; ++c) {
        float4 v = arow[c * 64 + lane];
        float f[4] = {v.x, v.y, v.z, v.w};
        #pragma unroll
        for (int j = 0; j < 4; ++j) {
            unsigned long long m = __ballot(f[j] != 0.0f);
            if (f[j] != 0.0f) {
                int pos = total + __popcll(m & ((1ull << lane) - 1ull));
                if (pos < CAP_) dst[pos] = (ushort_t)(c * 256 + lane * 4 + j);
            }
            total += __popcll(m);
        }
    }
    if (lane == 0) {
        nnz[row] = total < CAP_ ? total : CAP_;
        invdeg[row] = 1.0f / (float)(total + 1);
    }
}

// ---------------------------------------------------------------------------
// K2: barrier-free GEMM  Y[row, colBase:colBase+64] (+)= X[row, kBase:kBase+128]
//                                                       @ W[cols, kBase:+128]^T
// BM=128 (4 waves x 32 rows), BN=64, KTILE=128.
// W col-slab loaded to LDS once (k-major), ONE barrier total. Each wave then
// streams its private X rows through a per-wave LDS slab: same-wave DS
// ordering makes it correct with NO further __syncthreads, so global-load
// stalls never serialize other waves.
// GATHER: X row = emb[sent[row]] (fused embedding). ADD: out += (split-K pass 2).
// ---------------------------------------------------------------------------
template <int WSTRIDE, int XSTRIDE, bool GATHER, bool ADD>
__global__ __launch_bounds__(256, 2) void k_gemm(const float* __restrict__ X,
                                                 const int* __restrict__ sent,
                                                 const float* __restrict__ emb,
                                                 const float* __restrict__ W,
                                                 int kBase,
                                                 float* __restrict__ out) {
    __shared__ float Ws[128][68];    // [k][j]  (34816 B)
    __shared__ float Xs[4][16][36];  // per-wave [k][row32] (9216 B) -> 44 KB total
    int tid  = threadIdx.x;
    int wave = tid >> 6, lane = tid & 63;
    int rb       = blockIdx.x >> 1;
    int colBase  = (blockIdx.x & 1) * 64;
    int rowBase  = rb * 128 + wave * 32;

    // ---- one-time W slab preload (transpose to k-major) ----
    {
        int j  = tid & 63;
        int kq = tid >> 6;                 // k range kq*32..+31
        const float* wp = W + (size_t)(colBase + j) * WSTRIDE + kBase + kq * 32;
        #pragma unroll
        for (int i = 0; i < 8; ++i) {
            float4 v = *(const float4*)(wp + i * 4);
            int k = kq * 32 + i * 4;
            Ws[k + 0][j] = v.x; Ws[k + 1][j] = v.y;
            Ws[k + 2][j] = v.z; Ws[k + 3][j] = v.w;
        }
    }

    int cc = lane & 15, rr = lane >> 4;    // micro-tile: 8 rows (rr*8..) x 4 cols (cc*4..)
    int kg = lane & 3,  rowi = lane >> 2;  // staging: 2 rows (rowi, rowi+16), float4 k-group kg

    const float* xs0;
    const float* xs1;
    if (GATHER) {
        xs0 = emb + (size_t)sent[rowBase + rowi]      * XSTRIDE + kBase + kg * 4;
        xs1 = emb + (size_t)sent[rowBase + rowi + 16] * XSTRIDE + kBase + kg * 4;
    } else {
        xs0 = X + (size_t)(rowBase + rowi)      * XSTRIDE + kBase + kg * 4;
        xs1 = X + (size_t)(rowBase + rowi + 16) * XSTRIDE + kBase + kg * 4;
    }
    float4 f0 = *(const float4*)(xs0);
    float4 f1 = *(const float4*)(xs1);

    __syncthreads();                       // Ws ready; the ONLY barrier

    float acc[8][4] = {};
    float (*xsw)[36] = Xs[wave];

    #pragma unroll 1
    for (int kk = 0; kk < 128; kk += 16) {
        // transpose-store current chunk into this wave's private slab
        xsw[kg * 4 + 0][rowi] = f0.x; xsw[kg * 4 + 1][rowi] = f0.y;
        xsw[kg * 4 + 2][rowi] = f0.z; xsw[kg * 4 + 3][rowi] = f0.w;
        xsw[kg * 4 + 0][rowi + 16] = f1.x; xsw[kg * 4 + 1][rowi + 16] = f1.y;
        xsw[kg * 4 + 2][rowi + 16] = f1.z; xsw[kg * 4 + 3][rowi + 16] = f1.w;
        if (kk + 16 < 128) {               // prefetch next chunk (latency hidden)
            f0 = *(const float4*)(xs0 + kk + 16);
            f1 = *(const float4*)(xs1 + kk + 16);
        }
        #pragma unroll
        for (int k = 0; k < 16; ++k) {
            float4 x0 = *(const float4*)&xsw[k][rr * 8];
            float4 x1 = *(const float4*)&xsw[k][rr * 8 + 4];
            float4 wv = *(const float4*)&Ws[kk + k][cc * 4];
            float xv[8] = {x0.x, x0.y, x0.z, x0.w, x1.x, x1.y, x1.z, x1.w};
            #pragma unroll
            for (int i = 0; i < 8; ++i) {
                acc[i][0] += xv[i] * wv.x;
                acc[i][1] += xv[i] * wv.y;
                acc[i][2] += xv[i] * wv.z;
                acc[i][3] += xv[i] * wv.w;
            }
        }
    }

    #pragma unroll
    for (int i = 0; i < 8; ++i) {
        int row = rowBase + rr * 8 + i;
        float* op = out + (size_t)row * H_ + colBase + cc * 4;
        float4 o = {acc[i][0], acc[i][1], acc[i][2], acc[i][3]};
        if (ADD) {
            float4 p = *(const float4*)op;
            o.x += p.x; o.y += p.y; o.z += p.z; o.w += p.w;
        }
        *(float4*)op = o;
    }
}

// ---------------------------------------------------------------------------
// K3: aggregate + epilogue:
//   h[row] = relu( (Y[row] + sum_{t in nbr(row)} Y[b,t] + 2b) * invdeg[row] )
// XCD-swizzled; POOL fuses the AdaptiveMaxPool partial for layer 3.
// ---------------------------------------------------------------------------
template <bool POOL>
__global__ __launch_bounds__(256) void k_aggf(const float* __restrict__ Y,
                                              const ushort_t* __restrict__ idxl,
                                              const int* __restrict__ nnz,
                                              const float* __restrict__ invdeg,
                                              const float* __restrict__ bias,
                                              float* __restrict__ out) {
    int x    = blockIdx.x;            // 0..4095
    int xcd  = x & 7;
    int slot = x >> 3;                // 0..511
    int b    = xcd + 8 * (slot >> 6); // fixed xcd per batch
    int g    = slot & 63;
    int r    = threadIdx.x >> 5;      // 0..7
    int row  = b * S_ + g * 8 + r;
    int c    = threadIdx.x & 31;

    const float4* Y4 = (const float4*)Y;
    int n = nnz[row];
    const ushort_t* il = idxl + (size_t)row * CAP_;
    float4 acc = Y4[(size_t)row * 32 + c];
    float4 acc2 = {0.f, 0.f, 0.f, 0.f};
    size_t base = (size_t)b * S_ * 32;

    int i = 0;
    for (; i + 4 <= n; i += 4) {
        int t0 = il[i], t1 = il[i + 1], t2 = il[i + 2], t3 = il[i + 3];
        float4 v0 = Y4[base + (size_t)t0 * 32 + c];
        float4 v1 = Y4[base + (size_t)t1 * 32 + c];
        float4 v2 = Y4[base + (size_t)t2 * 32 + c];
        float4 v3 = Y4[base + (size_t)t3 * 32 + c];
        acc.x += v0.x + v1.x; acc.y += v0.y + v1.y;
        acc.z += v0.z + v1.z; acc.w += v0.w + v1.w;
        acc2.x += v2.x + v3.x; acc2.y += v2.y + v3.y;
        acc2.z += v2.z + v3.z; acc2.w += v2.w + v3.w;
    }
    for (; i < n; ++i) {
        int t = il[i];
        float4 v = Y4[base + (size_t)t * 32 + c];
        acc.x += v.x; acc.y += v.y; acc.z += v.z; acc.w += v.w;
    }
    acc.x += acc2.x; acc.y += acc2.y; acc.z += acc2.z; acc.w += acc2.w;

    float inv = invdeg[row];
    float4 bv = ((const float4*)bias)[c];
    float4 o;
    o.x = fmaxf((acc.x + 2.0f * bv.x) * inv, 0.0f);
    o.y = fmaxf((acc.y + 2.0f * bv.y) * inv, 0.0f);
    o.z = fmaxf((acc.z + 2.0f * bv.z) * inv, 0.0f);
    o.w = fmaxf((acc.w + 2.0f * bv.w) * inv, 0.0f);

    if (!POOL) {
        ((float4*)out)[(size_t)row * 32 + c] = o;
    } else {
        __shared__ float4 sm[8][33];
        sm[r][c] = o;
        __syncthreads();
        if (r == 0) {
            float4 m = sm[0][c];
            #pragma unroll
            for (int q = 1; q < 8; ++q) {
                float4 v = sm[q][c];
                m.x = fmaxf(m.x, v.x); m.y = fmaxf(m.y, v.y);
                m.z = fmaxf(m.z, v.z); m.w = fmaxf(m.w, v.w);
            }
            ((float4*)out)[((size_t)b * 64 + g) * 32 + c] = m;   // pp partial
        }
    }
}

// ---------------------------------------------------------------------------
// K4: finish pool (64 partials) + logits[b,c] = pooled . Wp[c,:] + bp[c]
// ---------------------------------------------------------------------------
__global__ void k_final(const float* __restrict__ pp,
                        const float* __restrict__ Wp,
                        const float* __restrict__ bp,
                        float* __restrict__ out) {
    int b = blockIdx.x, j = threadIdx.x;  // 128 threads
    const float* p = pp + (size_t)b * 64 * H_ + j;
    float m = -1e30f;
    #pragma unroll 8
    for (int i = 0; i < 64; ++i) m = fmaxf(m, p[(size_t)i * H_]);
    float t0 = m * Wp[j];
    float t1 = m * Wp[H_ + j];
    #pragma unroll
    for (int off = 32; off > 0; off >>= 1) {
        t0 += __shfl_down(t0, off);
        t1 += __shfl_down(t1, off);
    }
    __shared__ float red[2][2];
    int wave = j >> 6, lane = j & 63;
    if (lane == 0) { red[0][wave] = t0; red[1][wave] = t1; }
    __syncthreads();
    if (j == 0) out[b * 2 + 0] = red[0][0] + red[0][1] + bp[0];
    if (j == 1) out[b * 2 + 1] = red[1][0] + red[1][1] + bp[1];
}

// ---------------------------------------------------------------------------
extern "C" void kernel_launch(void* const* d_in, const int* in_sizes, int n_in,
                              void* d_out, int out_size, void* d_ws, size_t ws_size,
                              hipStream_t stream) {
    const int*   sent = (const int*)d_in[0];
    const float* adj  = (const float*)d_in[1];
    const float* emb  = (const float*)d_in[2];
    const float* W1   = (const float*)d_in[3];
    const float* b1   = (const float*)d_in[4];
    const float* W2   = (const float*)d_in[5];
    const float* b2   = (const float*)d_in[6];
    const float* W3   = (const float*)d_in[7];
    const float* b3   = (const float*)d_in[8];
    const float* Wp   = (const float*)d_in[9];
    const float* bp   = (const float*)d_in[10];
    float* out = (float*)d_out;

    char* ws = (char*)d_ws;
    float*    bufA   = (float*)ws;                                  // M*128 f32
    float*    bufB   = (float*)(ws + (size_t)M_ * 256 * 4);         // M*128 f32
    float*    invdeg = (float*)(ws + (size_t)M_ * 512 * 4);         // M f32
    int*      nnz    = (int*)(ws + (size_t)M_ * 512 * 4 + M_ * 4);
    ushort_t* idxl   = (ushort_t*)(ws + (size_t)M_ * 512 * 4 + M_ * 8);          // M*CAP u16
    float*    pp     = (float*)(ws + (size_t)M_ * 512 * 4 + M_ * 8 + (size_t)M_ * CAP_ * 2);  // 64*64*128 f32

    k_adjidx<<<M_ / 4, 256, 0, stream>>>(adj, idxl, nnz, invdeg);

    // layer 1: Y1 = emb[sent] @ W1^T  — split-K (2 x KTILE=128), fused gather
    k_gemm<E_, E_, true, false><<<512, 256, 0, stream>>>(nullptr, sent, emb, W1, 0,   bufA);
    k_gemm<E_, E_, true, true ><<<512, 256, 0, stream>>>(nullptr, sent, emb, W1, 128, bufA);
    k_aggf<false><<<M_ / 8, 256, 0, stream>>>(bufA, idxl, nnz, invdeg, b1, bufB);

    // layer 2
    k_gemm<H_, H_, false, false><<<512, 256, 0, stream>>>(bufB, nullptr, nullptr, W2, 0, bufA);
    k_aggf<false><<<M_ / 8, 256, 0, stream>>>(bufA, idxl, nnz, invdeg, b2, bufB);

    // layer 3: agg + fused max-pool partials
    k_gemm<H_, H_, false, false><<<512, 256, 0, stream>>>(bufB, nullptr, nullptr, W3, 0, bufA);
    k_aggf<true><<<M_ / 8, 256, 0, stream>>>(bufA, idxl, nnz, invdeg, b3, pp);

    k_final<<<B_, H_, 0, stream>>>(pp, Wp, bp, out);
}